// Round 5
// baseline (144.378 us; speedup 1.0000x reference)
//
#include <hip/hip_runtime.h>
#include <stdint.h>

// KAN layer as bf16 MFMA GEMM: out = phi @ W^T + bias
//   phi[b, i*8+g] = normalized cubic-bump basis (g<5; 3 zero-pad cols)
// M=32768, N=256, K=2048 (64 kt-iters of BK=32).
// R5: NO LDS, NO BARRIERS in the K-loop. Wave tile 32x128 (4 m-waves per
//     block) makes every lane's A fragment a distinct (row,i) basis octet ->
//     computed straight into registers (R4's per-iter __syncthreads forced
//     vmcnt(0) drains that defeated the B register pipeline — the ~40% stall).
//     B from fragment-ordered Wf (L1/L2-resident), prefetched 2 iters ahead.
//     Basis uses float2 ext-vector ops -> v_pk_* packed math.

#define B_SZ   32768
#define IN_SZ  256
#define OUT_SZ 256
#define EPSF   1e-8f

typedef __bf16 bf16x8 __attribute__((ext_vector_type(8)));
typedef unsigned short ushort8 __attribute__((ext_vector_type(8)));
typedef float floatx16 __attribute__((ext_vector_type(16)));
typedef float float2v __attribute__((ext_vector_type(2)));

__device__ __forceinline__ unsigned short f2bf(float f) {
  unsigned u = __float_as_uint(f);
  u += 0x7FFFu + ((u >> 16) & 1u);
  return (unsigned short)(u >> 16);
}

// Wf fragment-order chunk index for (o, i): 16B chunk = 8 bf16 g-slots.
//   chunk = (((o>>5)*64 + (i>>2))*2 + ((i>>1)&1))*64 + (i&1)*32 + (o&31)
// gemm reads chunk = wave-uniform base + lane -> coalesced dwordx4.

// Fused prep: blocks [0,256) pack W into fragment order; [256,512) do
// per-block min/max partials of x.
__global__ void __launch_bounds__(256) prep_kernel(const float* __restrict__ coef,
                                                   const float* __restrict__ scale,
                                                   const float* __restrict__ x,
                                                   unsigned short* __restrict__ wf,
                                                   float* __restrict__ part, int n4) {
  const int t = threadIdx.x;
  if (blockIdx.x < 256) {
    int idx = blockIdx.x * 256 + t;        // o*256 + i
    int o = idx >> 8, i = idx & 255;
    float s = scale[idx];
    const float* c = coef + (size_t)idx * 5;
    ushort8 v;
    v[0] = f2bf(c[0] * s); v[1] = f2bf(c[1] * s); v[2] = f2bf(c[2] * s);
    v[3] = f2bf(c[3] * s); v[4] = f2bf(c[4] * s);
    v[5] = 0; v[6] = 0; v[7] = 0;
    int chunk = (((o >> 5) * 64 + (i >> 2)) * 2 + ((i >> 1) & 1)) * 64
                + (i & 1) * 32 + (o & 31);
    *(ushort8*)(wf + (size_t)chunk * 8) = v;
  } else {
    int mb = blockIdx.x - 256;
    const float4* x4 = (const float4*)x;
    float lmin = 1e30f, lmax = -1e30f;
    for (int i = mb * 256 + t; i < n4; i += 256 * 256) {
      float4 v = x4[i];
      lmin = fminf(lmin, fminf(fminf(v.x, v.y), fminf(v.z, v.w)));
      lmax = fmaxf(lmax, fmaxf(fmaxf(v.x, v.y), fmaxf(v.z, v.w)));
    }
    #pragma unroll
    for (int off = 32; off >= 1; off >>= 1) {
      lmin = fminf(lmin, __shfl_down(lmin, off, 64));
      lmax = fmaxf(lmax, __shfl_down(lmax, off, 64));
    }
    __shared__ float smn[4], smx[4];
    if ((t & 63) == 0) { smn[t >> 6] = lmin; smx[t >> 6] = lmax; }
    __syncthreads();
    if (t == 0) {
      part[2 * mb]     = fminf(fminf(smn[0], smn[1]), fminf(smn[2], smn[3]));
      part[2 * mb + 1] = fmaxf(fmaxf(smx[0], smx[1]), fmaxf(smx[2], smx[3]));
    }
  }
}

__global__ void __launch_bounds__(256, 2) kan_gemm(
    const float* __restrict__ x,            // [32768][256]
    const unsigned short* __restrict__ wf,  // fragment-ordered W, 1 MB
    const float* __restrict__ bias,         // [256]
    const float* __restrict__ part,         // 256 {min,max} partials
    float* __restrict__ out)                // [32768][256]
{
  __shared__ float2 red[4];

  const int t = threadIdx.x;
  const int lane = t & 63;
  const int wm = t >> 6;                     // 4 waves stacked in m
  const int l31 = lane & 31, lh = lane >> 5;
  const int bRow = blockIdx.x * 128;
  const int bCol = blockIdx.y * 128;
  const int row = bRow + wm * 32 + l31;      // this lane's A row

  // ---- issue first B/x loads before the minmax reduce (hide L2 latency) ----
  const unsigned short* bp[4];               // per-ni base, points at kt=0
  #pragma unroll
  for (int ni = 0; ni < 4; ++ni)
    bp[ni] = wf + (size_t)(blockIdx.y * 4 + ni) * 65536 + (size_t)lane * 8;
  const float* xp = x + (size_t)row * IN_SZ; // points at kt=0

  bf16x8 bReg[2][2][4];                      // [parity][ks][ni]
  float4 xq[2];
  #pragma unroll
  for (int u = 0; u < 2; ++u) {
    xq[u] = *(const float4*)(xp + u * 4);
    #pragma unroll
    for (int ks = 0; ks < 2; ++ks)
      #pragma unroll
      for (int ni = 0; ni < 4; ++ni)
        bReg[u][ks][ni] = *(const bf16x8*)(bp[ni] + u * 1024 + ks * 512);
  }
  xp += 8;
  #pragma unroll
  for (int ni = 0; ni < 4; ++ni) bp[ni] += 2048;   // now at kt=2

  // ---- minmax finale (one barrier, outside the K-loop) ----
  float2 p = ((const float2*)part)[t];
  float mn = p.x, mx = p.y;
  #pragma unroll
  for (int off = 32; off >= 1; off >>= 1) {
    mn = fminf(mn, __shfl_down(mn, off, 64));
    mx = fmaxf(mx, __shfl_down(mx, off, 64));
  }
  if (lane == 0) red[wm] = make_float2(mn, mx);
  __syncthreads();
  mn = fminf(fminf(red[0].x, red[1].x), fminf(red[2].x, red[3].x));
  mx = fmaxf(fmaxf(red[0].y, red[1].y), fmaxf(red[2].y, red[3].y));
  const float scA = 2.0f / (mx - mn + EPSF);
  const float scB = -mn * scA - 1.0f;

  // one basis octet -> A fragment, packed-f32 math.
  // where(d<1, 1-d^3, 0) == max(1 - d*d*|d|, 0) ; grid {-1,-.5,0,.5,1}
  auto basisfrag = [&](float xval) -> bf16x8 {
    float xn = fmaf(xval, scA, scB);
    float2v xx = {xn, xn};
    float2v dA = xx + (float2v){1.0f, 0.5f};       // d0, d1
    float2v dB = xx - (float2v){0.5f, 1.0f};       // d3, d4
    float2v aA = __builtin_elementwise_max(dA, -dA);
    float2v aB = __builtin_elementwise_max(dB, -dB);
    float2v one2 = {1.0f, 1.0f};
    float2v z2 = {0.0f, 0.0f};
    float2v bA = __builtin_elementwise_max(one2 - dA * dA * aA, z2);
    float2v bB = __builtin_elementwise_max(one2 - dB * dB * aB, z2);
    float b2 = fmaxf(fmaf(xn * xn, -fabsf(xn), 1.0f), 0.0f);
    float sum = (bA.x + bA.y) + (bB.x + bB.y) + (b2 + EPSF);
    float inv = __builtin_amdgcn_rcpf(sum);
    float2v sA = bA * inv;
    float2v sB = bB * inv;
    bf16x8 av = {};
    av[0] = (__bf16)sA.x; av[1] = (__bf16)sA.y; av[2] = (__bf16)(b2 * inv);
    av[3] = (__bf16)sB.x; av[4] = (__bf16)sB.y;
    return av;
  };

  floatx16 acc[4] = {};

  // ---- barrier-free K loop ----
  for (int base = 0; base < 64; base += 2) {
    #pragma unroll
    for (int u = 0; u < 2; ++u) {
      const int kt = base + u;

      // A fragments from registers: i = kt*4 + ks*2 + lh
      float xv0 = lh ? xq[u].y : xq[u].x;    // ks=0
      float xv1 = lh ? xq[u].w : xq[u].z;    // ks=1
      bf16x8 af0 = basisfrag(xv0);
      bf16x8 af1 = basisfrag(xv1);

      #pragma unroll
      for (int ni = 0; ni < 4; ++ni)
        acc[ni] = __builtin_amdgcn_mfma_f32_32x32x16_bf16(af0, bReg[u][0][ni], acc[ni], 0, 0, 0);
      #pragma unroll
      for (int ni = 0; ni < 4; ++ni)
        acc[ni] = __builtin_amdgcn_mfma_f32_32x32x16_bf16(af1, bReg[u][1][ni], acc[ni], 0, 0, 0);

      // prefetch kt+2 into this parity (no barrier ever drains these)
      if (kt < 62) {
        xq[u] = *(const float4*)(xp + u * 4);
        #pragma unroll
        for (int ks = 0; ks < 2; ++ks)
          #pragma unroll
          for (int ni = 0; ni < 4; ++ni)
            bReg[u][ks][ni] = *(const bf16x8*)(bp[ni] + u * 1024 + ks * 512);
      }
    }
    xp += 8;
    #pragma unroll
    for (int ni = 0; ni < 4; ++ni) bp[ni] += 2048;
  }

  // epilogue: C/D col=lane&31, row=(reg&3)+8*(reg>>2)+4*(lane>>5) [m74/m101]
  #pragma unroll
  for (int ni = 0; ni < 4; ++ni) {
    int o = bCol + ni * 32 + l31;
    float bs = bias[o];
    int rb = bRow + wm * 32 + 4 * lh;
    #pragma unroll
    for (int reg = 0; reg < 16; ++reg) {
      int r = rb + (reg & 3) + 8 * (reg >> 2);
      out[(size_t)r * OUT_SZ + o] = acc[ni][reg] + bs;
    }
  }
}

extern "C" void kernel_launch(void* const* d_in, const int* in_sizes, int n_in,
                              void* d_out, int out_size, void* d_ws, size_t ws_size,
                              hipStream_t stream) {
  const float* x     = (const float*)d_in[0];
  // d_in[1] = grid: linspace(-1,1,5), hardcoded
  const float* coef  = (const float*)d_in[2];
  const float* scale = (const float*)d_in[3];
  const float* bias  = (const float*)d_in[4];
  float* out = (float*)d_out;

  // ws: [0..2048) minmax partials (256 float2), [4096..) Wf (1 MB)
  size_t need = 4096 + (size_t)OUT_SZ * IN_SZ * 8 * 2;
  if (ws_size < need) return;

  float* part = (float*)d_ws;
  unsigned short* wf = (unsigned short*)((char*)d_ws + 4096);

  prep_kernel<<<512, 256, 0, stream>>>(coef, scale, x, wf, part,
                                       (B_SZ * IN_SZ) / 4);
  dim3 g(B_SZ / 128, OUT_SZ / 128);
  kan_gemm<<<g, 256, 0, stream>>>(x, wf, bias, part, out);
}

// Round 6
// 139.483 us; speedup vs baseline: 1.0351x; 1.0351x over previous
//
#include <hip/hip_runtime.h>
#include <stdint.h>

// KAN layer as bf16 MFMA GEMM: out = phi @ W^T + bias
//   phi[b, i*8+g] = normalized cubic-bump basis (g<5; 3 zero-pad cols)
// M=32768, N=256, K=2048 (64 kt-iters of BK=32).
// R6: R5 was L2-read-BW-bound (4.6 MB/CU of B+x re-reads ≈ 34 µs floor at
//     135 GB/s/CU). B now staged into LDS in COARSE chunks (4 kt-iters,
//     32 KB, double-buffered) via global_load_lds: 1 barrier per 4 iters,
//     whose mandatory vmcnt(0) drain IS the DMA wait we need (fixes R4's
//     per-iter-barrier pipeline kill). A (basis) stays register-direct
//     (R5 trick: wave tile 32x128 -> zero basis duplication in block).
//     LDS read traffic 4.1 MB/CU at ~204 GB/s/CU on its own pipe.

#define B_SZ   32768
#define IN_SZ  256
#define OUT_SZ 256
#define EPSF   1e-8f

typedef __bf16 bf16x8 __attribute__((ext_vector_type(8)));
typedef unsigned short ushort8 __attribute__((ext_vector_type(8)));
typedef float floatx16 __attribute__((ext_vector_type(16)));
typedef float float2v __attribute__((ext_vector_type(2)));

__device__ __forceinline__ unsigned short f2bf(float f) {
  unsigned u = __float_as_uint(f);
  u += 0x7FFFu + ((u >> 16) & 1u);
  return (unsigned short)(u >> 16);
}

// Wf fragment-order chunk index for (o, i): 16B chunk = 8 bf16 g-slots.
//   chunk = (((o>>5)*64 + (i>>2))*2 + ((i>>1)&1))*64 + (i&1)*32 + (o&31)
// == ((oT*64 + kt)*2 + ks)*64 + lane, with o=oT*32+(lane&31), i=kt*4+ks*2+(lane>>5).

// Fused prep: blocks [0,256) pack W into fragment order; [256,512) do
// per-block min/max partials of x.
__global__ void __launch_bounds__(256) prep_kernel(const float* __restrict__ coef,
                                                   const float* __restrict__ scale,
                                                   const float* __restrict__ x,
                                                   unsigned short* __restrict__ wf,
                                                   float* __restrict__ part, int n4) {
  const int t = threadIdx.x;
  if (blockIdx.x < 256) {
    int idx = blockIdx.x * 256 + t;        // o*256 + i
    int o = idx >> 8, i = idx & 255;
    float s = scale[idx];
    const float* c = coef + (size_t)idx * 5;
    ushort8 v;
    v[0] = f2bf(c[0] * s); v[1] = f2bf(c[1] * s); v[2] = f2bf(c[2] * s);
    v[3] = f2bf(c[3] * s); v[4] = f2bf(c[4] * s);
    v[5] = 0; v[6] = 0; v[7] = 0;
    int chunk = (((o >> 5) * 64 + (i >> 2)) * 2 + ((i >> 1) & 1)) * 64
                + (i & 1) * 32 + (o & 31);
    *(ushort8*)(wf + (size_t)chunk * 8) = v;
  } else {
    int mb = blockIdx.x - 256;
    const float4* x4 = (const float4*)x;
    float lmin = 1e30f, lmax = -1e30f;
    for (int i = mb * 256 + t; i < n4; i += 256 * 256) {
      float4 v = x4[i];
      lmin = fminf(lmin, fminf(fminf(v.x, v.y), fminf(v.z, v.w)));
      lmax = fmaxf(lmax, fmaxf(fmaxf(v.x, v.y), fmaxf(v.z, v.w)));
    }
    #pragma unroll
    for (int off = 32; off >= 1; off >>= 1) {
      lmin = fminf(lmin, __shfl_down(lmin, off, 64));
      lmax = fmaxf(lmax, __shfl_down(lmax, off, 64));
    }
    __shared__ float smn[4], smx[4];
    if ((t & 63) == 0) { smn[t >> 6] = lmin; smx[t >> 6] = lmax; }
    __syncthreads();
    if (t == 0) {
      part[2 * mb]     = fminf(fminf(smn[0], smn[1]), fminf(smn[2], smn[3]));
      part[2 * mb + 1] = fmaxf(fmaxf(smx[0], smx[1]), fmaxf(smx[2], smx[3]));
    }
  }
}

__global__ void __launch_bounds__(256, 2) kan_gemm(
    const float* __restrict__ x,            // [32768][256]
    const unsigned short* __restrict__ wf,  // fragment-ordered W, 1 MB
    const float* __restrict__ bias,         // [256]
    const float* __restrict__ part,         // 256 {min,max} partials
    float* __restrict__ out)                // [32768][256]
{
  // B chunk buffers: [buf][ (oT*4+ktr)*2+ks ][ lane*16B ]  -> 2 x 32 KB
  __shared__ __align__(16) unsigned short Bb[2][16384];
  __shared__ float2 red[4];

  const int t = threadIdx.x;
  const int lane = t & 63;
  const int wm = t >> 6;                     // 4 waves stacked in m
  const int l31 = lane & 31, lh = lane >> 5;
  const int bRow = blockIdx.x * 128;
  const int bCol = blockIdx.y * 128;
  const int row = bRow + wm * 32 + l31;      // this lane's A row

  // ---- B chunk staging: 32 segments of 1 KB; each wave DMAs 8 (lane-linear) ----
  auto stage = [&](int c, int buf) {
    #pragma unroll
    for (int r = 0; r < 8; ++r) {
      int idx = r * 4 + wm;                  // wave-uniform; oT=idx>>3, ktr=(idx>>1)&3, ks=idx&1
      const unsigned short* src = wf +
          ((size_t)(((blockIdx.y * 4 + (idx >> 3)) * 64 + (c * 4 + ((idx >> 1) & 3))) * 2
                    + (idx & 1))) * 512 + (size_t)lane * 8;
      __builtin_amdgcn_global_load_lds(
          (const __attribute__((address_space(1))) unsigned int*)src,
          (__attribute__((address_space(3))) unsigned int*)(&Bb[buf][idx * 512 + lane * 8]),
          16, 0, 0);
    }
  };

  const float* xrow = x + (size_t)row * IN_SZ;

  // prologue: chunk 0 DMA + group-0 x loads in flight during minmax reduce
  stage(0, 0);
  float4 xq[4], xqn[4];
  #pragma unroll
  for (int g = 0; g < 4; ++g) xq[g] = *(const float4*)(xrow + g * 4);

  float2 p = ((const float2*)part)[t];
  float mn = p.x, mx = p.y;
  #pragma unroll
  for (int off = 32; off >= 1; off >>= 1) {
    mn = fminf(mn, __shfl_down(mn, off, 64));
    mx = fmaxf(mx, __shfl_down(mx, off, 64));
  }
  if (lane == 0) red[wm] = make_float2(mn, mx);
  __syncthreads();
  mn = fminf(fminf(red[0].x, red[1].x), fminf(red[2].x, red[3].x));
  mx = fmaxf(fmaxf(red[0].y, red[1].y), fmaxf(red[2].y, red[3].y));
  const float scA = 2.0f / (mx - mn + EPSF);
  const float scB = -mn * scA - 1.0f;

  // one basis octet -> A fragment; where(d<1,1-d^3,0) == max(1-d*d*|d|,0)
  auto basisfrag = [&](float xval) -> bf16x8 {
    float xn = fmaf(xval, scA, scB);
    float2v xx = {xn, xn};
    float2v dA = xx + (float2v){1.0f, 0.5f};
    float2v dB = xx - (float2v){0.5f, 1.0f};
    float2v aA = __builtin_elementwise_max(dA, -dA);
    float2v aB = __builtin_elementwise_max(dB, -dB);
    float2v one2 = {1.0f, 1.0f};
    float2v z2 = {0.0f, 0.0f};
    float2v bA = __builtin_elementwise_max(one2 - dA * dA * aA, z2);
    float2v bB = __builtin_elementwise_max(one2 - dB * dB * aB, z2);
    float b2 = fmaxf(fmaf(xn * xn, -fabsf(xn), 1.0f), 0.0f);
    float sum = (bA.x + bA.y) + (bB.x + bB.y) + (b2 + EPSF);
    float inv = __builtin_amdgcn_rcpf(sum);
    float2v sA = bA * inv;
    float2v sB = bB * inv;
    bf16x8 av = {};
    av[0] = (__bf16)sA.x; av[1] = (__bf16)sA.y; av[2] = (__bf16)(b2 * inv);
    av[3] = (__bf16)sB.x; av[4] = (__bf16)sB.y;
    return av;
  };

  floatx16 acc[4] = {};

  // ---- K loop: 16 groups x 4 kt-iters; ONE barrier per group ----
  for (int c = 0; c < 16; ++c) {
    const int buf = c & 1;

    __syncthreads();   // vmcnt(0) drain == wait for chunk-c DMA (issued 1 group
                       // ago) + xqn loads; also fences prev-buf LDS reads.

    if (c < 15) {      // issue next chunk's DMA + x loads NOW (full group in flight)
      stage(c + 1, buf ^ 1);
      #pragma unroll
      for (int g = 0; g < 4; ++g)
        xqn[g] = *(const float4*)(xrow + (c + 1) * 16 + g * 4);
    }

    #pragma unroll
    for (int ktr = 0; ktr < 4; ++ktr) {
      // A fragments from registers: i = (c*4+ktr)*4 + ks*2 + lh
      float xv0 = lh ? xq[ktr].y : xq[ktr].x;    // ks=0
      float xv1 = lh ? xq[ktr].w : xq[ktr].z;    // ks=1
      bf16x8 af0 = basisfrag(xv0);
      bf16x8 af1 = basisfrag(xv1);

      #pragma unroll
      for (int ni = 0; ni < 4; ++ni) {
        bf16x8 b0 = *(const bf16x8*)(&Bb[buf][((ni * 4 + ktr) * 2 + 0) * 512 + lane * 8]);
        acc[ni] = __builtin_amdgcn_mfma_f32_32x32x16_bf16(af0, b0, acc[ni], 0, 0, 0);
      }
      #pragma unroll
      for (int ni = 0; ni < 4; ++ni) {
        bf16x8 b1 = *(const bf16x8*)(&Bb[buf][((ni * 4 + ktr) * 2 + 1) * 512 + lane * 8]);
        acc[ni] = __builtin_amdgcn_mfma_f32_32x32x16_bf16(af1, b1, acc[ni], 0, 0, 0);
      }
    }

    #pragma unroll
    for (int g = 0; g < 4; ++g) xq[g] = xqn[g];
  }

  // epilogue: C/D col=lane&31, row=(reg&3)+8*(reg>>2)+4*(lane>>5) [m74/m101]
  #pragma unroll
  for (int ni = 0; ni < 4; ++ni) {
    int o = bCol + ni * 32 + l31;
    float bs = bias[o];
    int rb = bRow + wm * 32 + 4 * lh;
    #pragma unroll
    for (int reg = 0; reg < 16; ++reg) {
      int r = rb + (reg & 3) + 8 * (reg >> 2);
      out[(size_t)r * OUT_SZ + o] = acc[ni][reg] + bs;
    }
  }
}

extern "C" void kernel_launch(void* const* d_in, const int* in_sizes, int n_in,
                              void* d_out, int out_size, void* d_ws, size_t ws_size,
                              hipStream_t stream) {
  const float* x     = (const float*)d_in[0];
  // d_in[1] = grid: linspace(-1,1,5), hardcoded
  const float* coef  = (const float*)d_in[2];
  const float* scale = (const float*)d_in[3];
  const float* bias  = (const float*)d_in[4];
  float* out = (float*)d_out;

  // ws: [0..2048) minmax partials (256 float2), [4096..) Wf (1 MB)
  size_t need = 4096 + (size_t)OUT_SZ * IN_SZ * 8 * 2;
  if (ws_size < need) return;

  float* part = (float*)d_ws;
  unsigned short* wf = (unsigned short*)((char*)d_ws + 4096);

  prep_kernel<<<512, 256, 0, stream>>>(coef, scale, x, wf, part,
                                       (B_SZ * IN_SZ) / 4);
  dim3 g(B_SZ / 128, OUT_SZ / 128);
  kan_gemm<<<g, 256, 0, stream>>>(x, wf, bias, part, out);
}

// Round 7
// 136.367 us; speedup vs baseline: 1.0587x; 1.0229x over previous
//
#include <hip/hip_runtime.h>
#include <stdint.h>

// KAN layer as bf16 MFMA GEMM: out = phi @ W^T + bias
//   phi[b, i*8+g] = normalized cubic-bump basis (g<5; 3 zero-pad cols)
// M=32768, N=256, K=2048 (64 kt-iters of BK=32).
// R7 (on R6 structure): (1) lean basisfrag ~33 VALU instr (fma+abs/neg
//     modifiers, no eps, v_perm truncating bf16 pack) — was ~90 instr of
//     scalarized ext-vector + cvt chains; (2) B LDS->register prefetch one
//     ktr ahead (double reg buffer) — removes per-kt lgkm wait from the
//     critical path. R6 waves spent ~2100 cyc/kt vs ~600 accountable; both
//     latency terms are source-removable. LDS B-read floor ~20.5 us/CU.

#define B_SZ   32768
#define IN_SZ  256
#define OUT_SZ 256
#define EPSF   1e-8f

typedef __bf16 bf16x8 __attribute__((ext_vector_type(8)));
typedef unsigned short ushort8 __attribute__((ext_vector_type(8)));
typedef float floatx16 __attribute__((ext_vector_type(16)));

union frag_u { uint4 u; bf16x8 v; };

__device__ __forceinline__ unsigned short f2bf(float f) {
  unsigned u = __float_as_uint(f);
  u += 0x7FFFu + ((u >> 16) & 1u);
  return (unsigned short)(u >> 16);
}

// Wf fragment-order chunk index for (o, i): 16B chunk = 8 bf16 g-slots.
//   chunk = ((oT*64 + kt)*2 + ks)*64 + lane, o=oT*32+(lane&31), i=kt*4+ks*2+(lane>>5)

// Fused prep: blocks [0,256) pack W into fragment order; [256,512) do
// per-block min/max partials of x.
__global__ void __launch_bounds__(256) prep_kernel(const float* __restrict__ coef,
                                                   const float* __restrict__ scale,
                                                   const float* __restrict__ x,
                                                   unsigned short* __restrict__ wf,
                                                   float* __restrict__ part, int n4) {
  const int t = threadIdx.x;
  if (blockIdx.x < 256) {
    int idx = blockIdx.x * 256 + t;        // o*256 + i
    int o = idx >> 8, i = idx & 255;
    float s = scale[idx];
    const float* c = coef + (size_t)idx * 5;
    ushort8 v;
    v[0] = f2bf(c[0] * s); v[1] = f2bf(c[1] * s); v[2] = f2bf(c[2] * s);
    v[3] = f2bf(c[3] * s); v[4] = f2bf(c[4] * s);
    v[5] = 0; v[6] = 0; v[7] = 0;
    int chunk = (((o >> 5) * 64 + (i >> 2)) * 2 + ((i >> 1) & 1)) * 64
                + (i & 1) * 32 + (o & 31);
    *(ushort8*)(wf + (size_t)chunk * 8) = v;
  } else {
    int mb = blockIdx.x - 256;
    const float4* x4 = (const float4*)x;
    float lmin = 1e30f, lmax = -1e30f;
    for (int i = mb * 256 + t; i < n4; i += 256 * 256) {
      float4 v = x4[i];
      lmin = fminf(lmin, fminf(fminf(v.x, v.y), fminf(v.z, v.w)));
      lmax = fmaxf(lmax, fmaxf(fmaxf(v.x, v.y), fmaxf(v.z, v.w)));
    }
    #pragma unroll
    for (int off = 32; off >= 1; off >>= 1) {
      lmin = fminf(lmin, __shfl_down(lmin, off, 64));
      lmax = fmaxf(lmax, __shfl_down(lmax, off, 64));
    }
    __shared__ float smn[4], smx[4];
    if ((t & 63) == 0) { smn[t >> 6] = lmin; smx[t >> 6] = lmax; }
    __syncthreads();
    if (t == 0) {
      part[2 * mb]     = fminf(fminf(smn[0], smn[1]), fminf(smn[2], smn[3]));
      part[2 * mb + 1] = fmaxf(fmaxf(smx[0], smx[1]), fmaxf(smx[2], smx[3]));
    }
  }
}

// Lean basis octet: ~33 VALU. where(d<1,1-d^3,0) == max(1-d*d*|d|,0) (d>=0
// monotone). eps dropped: sum >= 0.98 always (nearest knot <= 0.25 away).
// bf16 pack by truncation: v_perm_b32 grabs high16 pairs (err <= 2^-8 rel,
// inside the 7.1e-2 budget; measured absmax headroom 4.5x).
__device__ __forceinline__ bf16x8 basisfrag(float xval, float scA, float scB) {
  float xn = fmaf(xval, scA, scB);
  float d0 = xn + 1.0f, d1 = xn + 0.5f, d3 = xn - 0.5f, d4 = xn - 1.0f;
  float b0 = fmaxf(fmaf(d0 * d0, -fabsf(d0), 1.0f), 0.0f);
  float b1 = fmaxf(fmaf(d1 * d1, -fabsf(d1), 1.0f), 0.0f);
  float b2 = fmaxf(fmaf(xn * xn, -fabsf(xn), 1.0f), 0.0f);
  float b3 = fmaxf(fmaf(d3 * d3, -fabsf(d3), 1.0f), 0.0f);
  float b4 = fmaxf(fmaf(d4 * d4, -fabsf(d4), 1.0f), 0.0f);
  float sum = ((b0 + b1) + (b2 + b3)) + b4;
  float inv = __builtin_amdgcn_rcpf(sum);
  b0 *= inv; b1 *= inv; b2 *= inv; b3 *= inv; b4 *= inv;
  frag_u r;
  r.u.x = __builtin_amdgcn_perm(__float_as_uint(b1), __float_as_uint(b0), 0x07060302u);
  r.u.y = __builtin_amdgcn_perm(__float_as_uint(b3), __float_as_uint(b2), 0x07060302u);
  r.u.z = __float_as_uint(b4) >> 16;
  r.u.w = 0u;
  return r.v;
}

__global__ void __launch_bounds__(256, 2) kan_gemm(
    const float* __restrict__ x,            // [32768][256]
    const unsigned short* __restrict__ wf,  // fragment-ordered W, 1 MB
    const float* __restrict__ bias,         // [256]
    const float* __restrict__ part,         // 256 {min,max} partials
    float* __restrict__ out)                // [32768][256]
{
  // B chunk buffers: [buf][ (ni*4+ktr)*2+ks ][ lane*16B ]  -> 2 x 32 KB
  __shared__ __align__(16) unsigned short Bb[2][16384];
  __shared__ float2 red[4];

  const int t = threadIdx.x;
  const int lane = t & 63;
  const int wm = t >> 6;                     // 4 waves stacked in m
  const int l31 = lane & 31, lh = lane >> 5;
  const int bRow = blockIdx.x * 128;
  const int bCol = blockIdx.y * 128;
  const int row = bRow + wm * 32 + l31;      // this lane's A row

  // ---- B chunk staging: 32 segments of 1 KB; each wave DMAs 8 (lane-linear) ----
  auto stage = [&](int c, int buf) {
    #pragma unroll
    for (int r = 0; r < 8; ++r) {
      int idx = r * 4 + wm;                  // wave-uniform
      const unsigned short* src = wf +
          ((size_t)(((blockIdx.y * 4 + (idx >> 3)) * 64 + (c * 4 + ((idx >> 1) & 3))) * 2
                    + (idx & 1))) * 512 + (size_t)lane * 8;
      __builtin_amdgcn_global_load_lds(
          (const __attribute__((address_space(1))) unsigned int*)src,
          (__attribute__((address_space(3))) unsigned int*)(&Bb[buf][idx * 512 + lane * 8]),
          16, 0, 0);
    }
  };

  const float* xrow = x + (size_t)row * IN_SZ;

  // prologue: chunk 0 DMA + group-0 x loads in flight during minmax reduce
  stage(0, 0);
  float4 xq[4], xqn[4];
  #pragma unroll
  for (int g = 0; g < 4; ++g) xq[g] = *(const float4*)(xrow + g * 4);

  float2 p = ((const float2*)part)[t];
  float mn = p.x, mx = p.y;
  #pragma unroll
  for (int off = 32; off >= 1; off >>= 1) {
    mn = fminf(mn, __shfl_down(mn, off, 64));
    mx = fmaxf(mx, __shfl_down(mx, off, 64));
  }
  if (lane == 0) red[wm] = make_float2(mn, mx);
  __syncthreads();
  mn = fminf(fminf(red[0].x, red[1].x), fminf(red[2].x, red[3].x));
  mx = fmaxf(fmaxf(red[0].y, red[1].y), fmaxf(red[2].y, red[3].y));
  const float scA = 2.0f / (mx - mn + EPSF);
  const float scB = -mn * scA - 1.0f;

  floatx16 acc[4] = {};
  bf16x8 br[2][8];                           // [ktr parity][ni*2+ks]

  auto ldsB = [&](int ktr, int buf, bf16x8* dst) {
    #pragma unroll
    for (int q = 0; q < 8; ++q) {            // q = ni*2+ks
      int ni = q >> 1, ks = q & 1;
      dst[q] = *(const bf16x8*)(&Bb[buf][((ni * 4 + ktr) * 2 + ks) * 512 + lane * 8]);
    }
  };

  // ---- K loop: 16 groups x 4 kt-iters; ONE barrier per group ----
  for (int c = 0; c < 16; ++c) {
    const int buf = c & 1;

    __syncthreads();   // vmcnt(0) drain == wait for chunk-c DMA (issued 1
                       // group ago); also fences prev-buf LDS reads.

    if (c < 15) {      // next chunk's DMA + x loads in flight for a full group
      stage(c + 1, buf ^ 1);
      #pragma unroll
      for (int g = 0; g < 4; ++g)
        xqn[g] = *(const float4*)(xrow + (c + 1) * 16 + g * 4);
    }

    ldsB(0, buf, br[0]);                     // group-leading fragment load

    #pragma unroll
    for (int ktr = 0; ktr < 4; ++ktr) {
      if (ktr < 3) ldsB(ktr + 1, buf, br[(ktr + 1) & 1]);  // prefetch next ktr

      // A fragments from registers: i = (c*4+ktr)*4 + ks*2 + lh
      float xv0 = lh ? xq[ktr].y : xq[ktr].x;    // ks=0
      float xv1 = lh ? xq[ktr].w : xq[ktr].z;    // ks=1
      bf16x8 af0 = basisfrag(xv0, scA, scB);
      bf16x8 af1 = basisfrag(xv1, scA, scB);

      bf16x8* B = br[ktr & 1];
      #pragma unroll
      for (int ni = 0; ni < 4; ++ni)
        acc[ni] = __builtin_amdgcn_mfma_f32_32x32x16_bf16(af0, B[ni * 2 + 0], acc[ni], 0, 0, 0);
      #pragma unroll
      for (int ni = 0; ni < 4; ++ni)
        acc[ni] = __builtin_amdgcn_mfma_f32_32x32x16_bf16(af1, B[ni * 2 + 1], acc[ni], 0, 0, 0);
    }

    if (c < 15) {
      #pragma unroll
      for (int g = 0; g < 4; ++g) xq[g] = xqn[g];
    }
  }

  // epilogue: C/D col=lane&31, row=(reg&3)+8*(reg>>2)+4*(lane>>5) [m74/m101]
  #pragma unroll
  for (int ni = 0; ni < 4; ++ni) {
    int o = bCol + ni * 32 + l31;
    float bs = bias[o];
    int rb = bRow + wm * 32 + 4 * lh;
    #pragma unroll
    for (int reg = 0; reg < 16; ++reg) {
      int r = rb + (reg & 3) + 8 * (reg >> 2);
      out[(size_t)r * OUT_SZ + o] = acc[ni][reg] + bs;
    }
  }
}

extern "C" void kernel_launch(void* const* d_in, const int* in_sizes, int n_in,
                              void* d_out, int out_size, void* d_ws, size_t ws_size,
                              hipStream_t stream) {
  const float* x     = (const float*)d_in[0];
  // d_in[1] = grid: linspace(-1,1,5), hardcoded
  const float* coef  = (const float*)d_in[2];
  const float* scale = (const float*)d_in[3];
  const float* bias  = (const float*)d_in[4];
  float* out = (float*)d_out;

  // ws: [0..2048) minmax partials (256 float2), [4096..) Wf (1 MB)
  size_t need = 4096 + (size_t)OUT_SZ * IN_SZ * 8 * 2;
  if (ws_size < need) return;

  float* part = (float*)d_ws;
  unsigned short* wf = (unsigned short*)((char*)d_ws + 4096);

  prep_kernel<<<512, 256, 0, stream>>>(coef, scale, x, wf, part,
                                       (B_SZ * IN_SZ) / 4);
  dim3 g(B_SZ / 128, OUT_SZ / 128);
  kan_gemm<<<g, 256, 0, stream>>>(x, wf, bias, part, out);
}